// Round 1
// baseline (147.729 us; speedup 1.0000x reference)
//
#include <hip/hip_runtime.h>
#include <hip/hip_bf16.h>

#define H 128
#define W 128
#define NPIX (H * W)          // 16384
#define NRING 4
#define NBIN 256
#define BLOCK 256
#define NWAVE 4               // 256/64

// One block per (batch, channel). Histogram the channel into per-wave,
// per-ring 256-bin histograms, then derive mean/std/median per ring.
__global__ __launch_bounds__(BLOCK) void radial_tokenizer_kernel(
    const float* __restrict__ img, float* __restrict__ out) {
    __shared__ unsigned int shist[NWAVE][NRING][NBIN];  // 16 KB

    const int bc = blockIdx.x;
    const int b = bc / 3;
    const int c = bc % 3;
    const int tid = threadIdx.x;
    const int wid = tid >> 6;
    const int lane = tid & 63;

    // zero histograms: 4096 u32 entries
    unsigned int* hflat = &shist[0][0][0];
    #pragma unroll
    for (int i = 0; i < (NWAVE * NRING * NBIN) / BLOCK; ++i)
        hflat[tid + i * BLOCK] = 0u;
    __syncthreads();

    // Phase 1: histogram. float4 loads, 16 per thread.
    const float4* src =
        reinterpret_cast<const float4*>(img + ((size_t)b * 3 + c) * NPIX);
    #pragma unroll 4
    for (int i = tid; i < NPIX / 4; i += BLOCK) {
        float4 f = src[i];
        // 4 consecutive pixels share a row (row = 32 float4s)
        int y = i >> 5;
        int x0 = (i & 31) * 4;
        int dy = y - 64;
        int dy2 = dy * dy;
        float vals[4] = {f.x, f.y, f.z, f.w};
        #pragma unroll
        for (int j = 0; j < 4; ++j) {
            int dx = x0 + j - 64;
            int d2 = dx * dx + dy2;
            if (d2 > 0 && d2 <= 4096) {
                int ring = (d2 <= 256) ? 0 : (d2 <= 1024) ? 1 : (d2 <= 2304) ? 2 : 3;
                int v = (int)floorf(vals[j] * 255.0f);
                atomicAdd(&shist[wid][ring][v], 1u);
            }
        }
    }
    __syncthreads();

    // Phase 2: wave `wid` reduces ring `wid`. Lane owns 4 contiguous bins.
    const int ring = wid;
    const int base = lane * 4;
    int cnt[4];
    int localCnt = 0, localSum = 0;
    long long localSq = 0;
    #pragma unroll
    for (int j = 0; j < 4; ++j) {
        int bin = base + j;
        unsigned int h = shist[0][ring][bin] + shist[1][ring][bin] +
                         shist[2][ring][bin] + shist[3][ring][bin];
        cnt[j] = (int)h;
        localCnt += (int)h;
        localSum += (int)h * bin;
        localSq += (long long)h * bin * bin;
    }

    // inclusive prefix scan of counts across the wave (bin order = lane order)
    int incl = localCnt;
    #pragma unroll
    for (int d = 1; d < 64; d <<= 1) {
        int t = __shfl_up(incl, d);
        if (lane >= d) incl += t;
    }
    const int n = __shfl(incl, 63);
    const int excl = incl - localCnt;

    // reductions for sum / sumsq
    int sum = localSum;
    long long sq = localSq;
    #pragma unroll
    for (int d = 32; d > 0; d >>= 1) {
        sum += __shfl_xor(sum, d);
        sq += __shfl_xor(sq, d);
    }

    // median: sorted positions k1=(n-1)/2, k2=n/2 (0-indexed)
    const int k1 = (n - 1) >> 1;
    const int k2 = n >> 1;
    int cand1 = -1, cand2 = -1;
    int run = excl;
    #pragma unroll
    for (int j = 0; j < 4; ++j) {
        if (k1 >= run && k1 < run + cnt[j]) cand1 = base + j;
        if (k2 >= run && k2 < run + cnt[j]) cand2 = base + j;
        run += cnt[j];
    }
    #pragma unroll
    for (int d = 32; d > 0; d >>= 1) {
        cand1 = max(cand1, __shfl_xor(cand1, d));
        cand2 = max(cand2, __shfl_xor(cand2, d));
    }

    if (lane == 0) {
        double mean = (double)sum / (double)n;
        double ex2 = (double)sq / (double)n;
        double var = ex2 - mean * mean;
        float sd = sqrtf((float)(var > 0.0 ? var : 0.0));
        float med = 0.5f * (float)(cand1 + cand2);
        float* o = out + ((size_t)b * NRING + ring) * 9;
        o[c] = (float)mean;
        o[3 + c] = sd;
        o[6 + c] = med;
    }
}

extern "C" void kernel_launch(void* const* d_in, const int* in_sizes, int n_in,
                              void* d_out, int out_size, void* d_ws, size_t ws_size,
                              hipStream_t stream) {
    const float* img = (const float*)d_in[0];
    float* out = (float*)d_out;
    const int B = in_sizes[0] / (3 * NPIX);  // 4096
    dim3 grid(B * 3);
    dim3 block(BLOCK);
    hipLaunchKernelGGL(radial_tokenizer_kernel, grid, block, 0, stream, img, out);
}

// Round 3
// 129.071 us; speedup vs baseline: 1.1446x; 1.1446x over previous
//
#include <hip/hip_runtime.h>
#include <hip/hip_bf16.h>

#define H 128
#define W 128
#define NPIX (H * W)          // 16384
#define NRING 4
#define NBIN 256
#define BLOCK 256
#define NWAVE 4               // 256/64
#define ITER (NPIX / 4 / BLOCK)  // 16 float4 iterations per thread

typedef float f32x4 __attribute__((ext_vector_type(4)));

// One block per (batch, channel). Histogram the channel into per-wave,
// per-ring 256-bin histograms, then derive mean/std/median per ring.
// __launch_bounds__(256,8): force VGPR<=64 so 8 waves/SIMD (32/CU) resident.
__global__ __launch_bounds__(BLOCK, 8) void radial_tokenizer_kernel(
    const float* __restrict__ img, float* __restrict__ out) {
    __shared__ unsigned int shist[NWAVE][NRING][NBIN];  // 16 KB

    const int bc = blockIdx.x;
    const int b = bc / 3;
    const int c = bc % 3;
    const int tid = threadIdx.x;
    const int wid = tid >> 6;
    const int lane = tid & 63;

    // zero histograms: 4096 u32 entries
    unsigned int* hflat = &shist[0][0][0];
    #pragma unroll
    for (int i = 0; i < (NWAVE * NRING * NBIN) / BLOCK; ++i)
        hflat[tid + i * BLOCK] = 0u;
    __syncthreads();

    // Phase 1: histogram. Double-buffered chunks of 4 vec4 loads (4-deep
    // prefetch, statically named registers — no runtime-indexed arrays).
    const f32x4* src =
        reinterpret_cast<const f32x4*>(img + ((size_t)b * 3 + c) * NPIX);

#define NTLOAD(p) __builtin_nontemporal_load(&(p))
#define PROCESS(f, idx)                                                     \
    {                                                                       \
        const int i_ = (idx);                                               \
        const int y_ = i_ >> 5;                                             \
        const int x0_ = (i_ & 31) << 2;                                     \
        const int dy_ = y_ - 64;                                            \
        const int dy2_ = dy_ * dy_;                                         \
        const float v0_ = (f).x, v1_ = (f).y, v2_ = (f).z, v3_ = (f).w;     \
        const float v_[4] = {v0_, v1_, v2_, v3_};                           \
        _Pragma("unroll")                                                   \
        for (int j_ = 0; j_ < 4; ++j_) {                                    \
            const int dx_ = x0_ + j_ - 64;                                  \
            const int d2_ = dx_ * dx_ + dy2_;                               \
            if (d2_ > 0 && d2_ <= 4096) {                                   \
                const int ring_ =                                           \
                    (d2_ > 256) + (d2_ > 1024) + (d2_ > 2304);              \
                const int val_ = (int)(v_[j_] * 255.0f); /* x>=0: trunc==floor */ \
                atomicAdd(&shist[wid][ring_][val_], 1u);                    \
            }                                                               \
        }                                                                   \
    }

    f32x4 a0 = NTLOAD(src[tid + 0 * BLOCK]);
    f32x4 a1 = NTLOAD(src[tid + 1 * BLOCK]);
    f32x4 a2 = NTLOAD(src[tid + 2 * BLOCK]);
    f32x4 a3 = NTLOAD(src[tid + 3 * BLOCK]);

    #pragma unroll 1
    for (int ch = 0; ch < ITER / 4; ++ch) {
        f32x4 b0 = a0, b1 = a1, b2 = a2, b3 = a3;
        if (ch < ITER / 4 - 1) {
            const int o = (ch + 1) * 4 * BLOCK + tid;
            b0 = NTLOAD(src[o + 0 * BLOCK]);
            b1 = NTLOAD(src[o + 1 * BLOCK]);
            b2 = NTLOAD(src[o + 2 * BLOCK]);
            b3 = NTLOAD(src[o + 3 * BLOCK]);
        }
        const int ibase = ch * 4 * BLOCK + tid;
        PROCESS(a0, ibase + 0 * BLOCK);
        PROCESS(a1, ibase + 1 * BLOCK);
        PROCESS(a2, ibase + 2 * BLOCK);
        PROCESS(a3, ibase + 3 * BLOCK);
        a0 = b0; a1 = b1; a2 = b2; a3 = b3;
    }
    __syncthreads();

    // Phase 2: wave `wid` reduces ring `wid`. Lane owns 4 contiguous bins.
    const int ring = wid;
    const int base = lane * 4;
    int cnt[4];
    int localCnt = 0, localSum = 0;
    long long localSq = 0;
    #pragma unroll
    for (int j = 0; j < 4; ++j) {
        int bin = base + j;
        unsigned int h = shist[0][ring][bin] + shist[1][ring][bin] +
                         shist[2][ring][bin] + shist[3][ring][bin];
        cnt[j] = (int)h;
        localCnt += (int)h;
        localSum += (int)h * bin;
        localSq += (long long)h * bin * bin;
    }

    // inclusive prefix scan of counts across the wave (bin order = lane order)
    int incl = localCnt;
    #pragma unroll
    for (int d = 1; d < 64; d <<= 1) {
        int t = __shfl_up(incl, d);
        if (lane >= d) incl += t;
    }
    const int n = __shfl(incl, 63);
    const int excl = incl - localCnt;

    // reductions for sum / sumsq
    int sum = localSum;
    long long sq = localSq;
    #pragma unroll
    for (int d = 32; d > 0; d >>= 1) {
        sum += __shfl_xor(sum, d);
        sq += __shfl_xor(sq, d);
    }

    // median: sorted positions k1=(n-1)/2, k2=n/2 (0-indexed)
    const int k1 = (n - 1) >> 1;
    const int k2 = n >> 1;
    int cand1 = -1, cand2 = -1;
    int run = excl;
    #pragma unroll
    for (int j = 0; j < 4; ++j) {
        if (k1 >= run && k1 < run + cnt[j]) cand1 = base + j;
        if (k2 >= run && k2 < run + cnt[j]) cand2 = base + j;
        run += cnt[j];
    }
    #pragma unroll
    for (int d = 32; d > 0; d >>= 1) {
        cand1 = max(cand1, __shfl_xor(cand1, d));
        cand2 = max(cand2, __shfl_xor(cand2, d));
    }

    if (lane == 0) {
        double mean = (double)sum / (double)n;
        double ex2 = (double)sq / (double)n;
        double var = ex2 - mean * mean;
        float sd = sqrtf((float)(var > 0.0 ? var : 0.0));
        float med = 0.5f * (float)(cand1 + cand2);
        float* o = out + ((size_t)b * NRING + ring) * 9;
        o[c] = (float)mean;
        o[3 + c] = sd;
        o[6 + c] = med;
    }
}

extern "C" void kernel_launch(void* const* d_in, const int* in_sizes, int n_in,
                              void* d_out, int out_size, void* d_ws, size_t ws_size,
                              hipStream_t stream) {
    const float* img = (const float*)d_in[0];
    float* out = (float*)d_out;
    const int B = in_sizes[0] / (3 * NPIX);  // 4096
    dim3 grid(B * 3);
    dim3 block(BLOCK);
    hipLaunchKernelGGL(radial_tokenizer_kernel, grid, block, 0, stream, img, out);
}